// Round 8
// baseline (163.563 us; speedup 1.0000x reference)
//
#include <hip/hip_runtime.h>
#include <hip/hip_bf16.h>
#include <stdint.h>

#define OUTF 4096
#define INF  4096
#define MROWS 4096
#define GS 32

typedef __attribute__((ext_vector_type(8))) __bf16 bf16x8;
typedef __attribute__((ext_vector_type(4))) float f32x4;

__device__ inline void gload_lds16(const void* g, void* l) {
    __builtin_amdgcn_global_load_lds(
        (const __attribute__((address_space(1))) void*)g,
        (__attribute__((address_space(3))) void*)l, 16, 0, 0);
}

// Gather the 12 packed bytes of group `gid` (harness stores int8 input as
// sign-extended int32, 4B per packed byte).
__device__ inline void load_group_bits(const int* __restrict__ wq, int gid,
                                       uint64_t& lo, uint64_t& hi) {
    const int4* p = (const int4*)(wq + (size_t)gid * 12);
    int4 A = p[0], B = p[1], C = p[2];
    uint32_t d0 = (uint32_t)(A.x & 255) | ((uint32_t)(A.y & 255) << 8) |
                  ((uint32_t)(A.z & 255) << 16) | ((uint32_t)(A.w & 255) << 24);
    uint32_t d1 = (uint32_t)(B.x & 255) | ((uint32_t)(B.y & 255) << 8) |
                  ((uint32_t)(B.z & 255) << 16) | ((uint32_t)(B.w & 255) << 24);
    uint32_t d2 = (uint32_t)(C.x & 255) | ((uint32_t)(C.y & 255) << 8) |
                  ((uint32_t)(C.z & 255) << 16) | ((uint32_t)(C.w & 255) << 24);
    lo = (uint64_t)d0 | ((uint64_t)d1 << 32);
    hi = (uint64_t)d1 | ((uint64_t)d2 << 32);
}

// ---------------- fused prepass: x->bf16 (blocks 0..8191), W dequant (rest) --
__global__ void prep_kernel(const float* __restrict__ x, __bf16* __restrict__ xb,
                            const int* __restrict__ wq, const float* __restrict__ wn,
                            __bf16* __restrict__ wb) {
    const int bid = blockIdx.x;
    if (bid < 8192) {
        int i = bid * 256 + threadIdx.x;  // 2M threads, 8 floats each
        const f32x4* xp = (const f32x4*)x;
        f32x4 a = xp[2 * i], b = xp[2 * i + 1];
        bf16x8 v = { (__bf16)a[0], (__bf16)a[1], (__bf16)a[2], (__bf16)a[3],
                     (__bf16)b[0], (__bf16)b[1], (__bf16)b[2], (__bf16)b[3] };
        ((bf16x8*)xb)[i] = v;
    } else {
        int gid = (bid - 8192) * 256 + threadIdx.x;  // one 32-elem group
        uint64_t lo, hi;
        load_group_bits(wq, gid, lo, hi);
        float nrm = wn[gid];
        float c2 = nrm * (2.0f / 7.0f), c1 = -nrm;  // w = q*(2n/7) - n
        bf16x8 o[4];
#pragma unroll
        for (int j = 0; j < 32; ++j) {
            uint32_t q = (j <= 20) ? (uint32_t)((lo >> (3 * j)) & 7)
                                   : (uint32_t)((hi >> (3 * j - 32)) & 7);
            o[j >> 3][j & 7] = (__bf16)((float)q * c2 + c1);
        }
        bf16x8* outp = (bf16x8*)(wb + (size_t)gid * 32);
        outp[0] = o[0]; outp[1] = o[1]; outp[2] = o[2]; outp[3] = o[3];
    }
}

// ======== 256x128 tile GEMM, BK=32, triple-buffered, 2 blocks/CU ========
// Grid 512 (16 bm x 32 bn) -> 2 co-resident blocks per CU: their DS-read /
// MFMA / stage windows interleave across blocks (the intra-block barrier
// serialization measured in R4-R7 is hidden by the partner block).
// 512 thr = 8 waves (4Mx2N), per-wave 64x64 (acc 4x4 f32x4, ~110 VGPR).
// LDS 3 x 24KB buffers: [A 256x32][B 128x32] bf16, rows = 64B = 4 chunks,
// chunk swizzle ch ^= (r&3)^((r>>2)&3) (both sides; 2-way floor = free).
// Per K-tile t: VMCNT(3) [stage(t) landed, stage(t+1)=3 in flight, 2-tile
// slack]; barrier; stage(t+2) into buf (t+2)%3 (WAR-safe: last read t-1);
// read 8 b128; 16 MFMA. One barrier, one counted vmcnt per tile.

#define VMCNTQ(N) asm volatile("s_waitcnt vmcnt(" #N ")" ::: "memory")
#define BARR() do { asm volatile("" ::: "memory"); __builtin_amdgcn_s_barrier(); \
                    asm volatile("" ::: "memory"); } while (0)

#define STAGE3(SOFF, SKT) do { \
    gload_lds16(pa0 + (SKT) * 32, lds + (SOFF) + tid * 16); \
    gload_lds16(pa1 + (SKT) * 32, lds + (SOFF) + 8192 + tid * 16); \
    gload_lds16(pb0 + (SKT) * 32, lds + (SOFF) + 16384 + tid * 16); \
} while (0)

#define RD(ROFF) do { \
    _Pragma("unroll") \
    for (int m_ = 0; m_ < 4; ++m_) \
        af[m_] = *(const bf16x8*)(lds + (ROFF) + (wr * 64 + m_ * 16 + row16) * 64 + swl); \
    _Pragma("unroll") \
    for (int n_ = 0; n_ < 4; ++n_) \
        bf[n_] = *(const bf16x8*)(lds + (ROFF) + 16384 + (wc * 64 + n_ * 16 + row16) * 64 + swl); \
} while (0)

#define MFMA16() do { \
    __builtin_amdgcn_s_setprio(1); \
    _Pragma("unroll") \
    for (int m_ = 0; m_ < 4; ++m_) \
        _Pragma("unroll") \
        for (int n_ = 0; n_ < 4; ++n_) \
            acc[m_][n_] = __builtin_amdgcn_mfma_f32_16x16x32_bf16( \
                af[m_], bf[n_], acc[m_][n_], 0, 0, 0); \
    __builtin_amdgcn_s_setprio(0); \
} while (0)

#define ROT(V) do { (V) += 24576; if ((V) == 3 * 24576) (V) = 0; } while (0)

__global__ __launch_bounds__(512, 4) void gemm3_kernel(
    const __bf16* __restrict__ xb, const __bf16* __restrict__ wb,
    const float* __restrict__ bias, float* __restrict__ out) {
    __shared__ __align__(16) unsigned char lds[3 * 24576];

    const int tid = threadIdx.x;
    const int lane = tid & 63, wid = tid >> 6;
    const int wr = wid >> 1, wc = wid & 1;
    const int row16 = lane & 15, kq = lane >> 4;
    const int swl = (kq ^ ((row16 & 3) ^ ((row16 >> 2) & 3))) * 16;

    // XCD chunked swizzle: 512 wgs, 64 consecutive per XCD (bijective)
    const int bid = blockIdx.x;
    const int wg = (bid & 7) * 64 + (bid >> 3);
    const int bm = wg >> 5, bn = wg & 31;

    // staging geometry: linear LDS dest (slot*16), pre-swizzled global chunk
    const int ar0 = tid >> 2;
    const int ac0 = ((tid & 3) ^ ((ar0 & 3) ^ ((ar0 >> 2) & 3))) * 8;
    const int ar1 = (tid + 512) >> 2;
    const int ac1 = ((tid & 3) ^ ((ar1 & 3) ^ ((ar1 >> 2) & 3))) * 8;
    const __bf16* pa0 = xb + (size_t)(bm * 256 + ar0) * INF + ac0;
    const __bf16* pa1 = xb + (size_t)(bm * 256 + ar1) * INF + ac1;
    const __bf16* pb0 = wb + (size_t)(bn * 128 + ar0) * INF + ac0;

    f32x4 acc[4][4] = {};
    bf16x8 af[4], bf[4];

    // prologue: stage tiles 0,1 -> outstanding 6 at loop entry
    STAGE3(0, 0);
    STAGE3(24576, 1);

    int roff = 0, soff = 2 * 24576;
    for (int kt = 0; kt < 126; ++kt) {
        VMCNTQ(3);            // stage(kt) landed; stage(kt+1) stays in flight
        BARR();
        STAGE3(soff, kt + 2);
        RD(roff);
        MFMA16();
        ROT(roff); ROT(soff);
    }
    // kt = 126 (no stage left to issue)
    VMCNTQ(3);
    BARR();
    RD(roff);
    MFMA16();
    ROT(roff);
    // kt = 127 (final: full drain)
    VMCNTQ(0);
    BARR();
    RD(roff);
    MFMA16();

    // epilogue: C = acc + bias (16x16 C layout: col=lane&15, row=kq*4+j)
#pragma unroll
    for (int n = 0; n < 4; ++n) {
        const int col = bn * 128 + wc * 64 + n * 16 + row16;
        const float bv = bias[col];
#pragma unroll
        for (int m = 0; m < 4; ++m) {
            const int rbase = bm * 256 + wr * 64 + m * 16 + kq * 4;
#pragma unroll
            for (int j = 0; j < 4; ++j)
                out[(size_t)(rbase + j) * OUTF + col] = acc[m][n][j] + bv;
        }
    }
}

// ---------------- fallback (no workspace): fused 128^2 kernel ----------------
__global__ __launch_bounds__(256, 2) void gemm_fb_kernel(
    const float* __restrict__ x, const int* __restrict__ wq,
    const float* __restrict__ wn, const float* __restrict__ bias,
    float* __restrict__ out) {
    __shared__ __align__(16) unsigned char lAraw[128 * 128];
    __shared__ __align__(16) unsigned char lBraw[128 * 128];

    const int tid = threadIdx.x;
    const int lane = tid & 63, wid = tid >> 6;
    const int wr = wid >> 1, wc = wid & 1;
    const int bn = blockIdx.x, bm = blockIdx.y;
    const int row16 = lane & 15, kq = lane >> 4;

    f32x4 acc[4][4] = {};

    int aoff[4], boff[4];
#pragma unroll
    for (int m = 0; m < 4; ++m) {
        int r = wr * 64 + m * 16 + row16;
        aoff[m] = r * 128 + ((kq * 16) ^ ((r & 7) << 4));
    }
#pragma unroll
    for (int n = 0; n < 4; ++n) {
        int r = wc * 64 + n * 16 + row16;
        boff[n] = r * 128 + ((kq * 16) ^ ((r & 7) << 4));
    }

    for (int kt = 0; kt < INF / 64; ++kt) {
        __syncthreads();
#pragma unroll
        for (int it = 0; it < 4; ++it) {
            int row = it * 32 + (tid >> 3), c = tid & 7;
            const f32x4* xp = (const f32x4*)(x + (size_t)(bm * 128 + row) * INF + kt * 64 + c * 8);
            f32x4 a0 = xp[0], a1 = xp[1];
            bf16x8 v = { (__bf16)a0[0], (__bf16)a0[1], (__bf16)a0[2], (__bf16)a0[3],
                         (__bf16)a1[0], (__bf16)a1[1], (__bf16)a1[2], (__bf16)a1[3] };
            *(bf16x8*)(lAraw + row * 128 + ((c * 16) ^ ((row & 7) << 4))) = v;
        }
        {
            int row = tid >> 1, gi = tid & 1;
            int gid = (bn * 128 + row) * (INF / GS) + kt * 2 + gi;
            uint64_t lo, hi;
            load_group_bits(wq, gid, lo, hi);
            float nrm = wn[gid];
            float c2 = nrm * (2.0f / 7.0f), c1 = -nrm;
            bf16x8 o[4];
#pragma unroll
            for (int j = 0; j < 32; ++j) {
                uint32_t q = (j <= 20) ? (uint32_t)((lo >> (3 * j)) & 7)
                                       : (uint32_t)((hi >> (3 * j - 32)) & 7);
                o[j >> 3][j & 7] = (__bf16)((float)q * c2 + c1);
            }
            unsigned swz = (row & 7) << 4;
#pragma unroll
            for (int c4 = 0; c4 < 4; ++c4)
                *(bf16x8*)(lBraw + row * 128 + ((gi * 64 + c4 * 16) ^ swz)) = o[c4];
        }
        __syncthreads();

#pragma unroll
        for (int kk = 0; kk < 2; ++kk) {
            bf16x8 afr[4], bfr[4];
#pragma unroll
            for (int m = 0; m < 4; ++m)
                afr[m] = *(const bf16x8*)(lAraw + (aoff[m] ^ (kk * 64)));
#pragma unroll
            for (int n = 0; n < 4; ++n)
                bfr[n] = *(const bf16x8*)(lBraw + (boff[n] ^ (kk * 64)));
#pragma unroll
            for (int m = 0; m < 4; ++m)
#pragma unroll
                for (int n = 0; n < 4; ++n)
                    acc[m][n] = __builtin_amdgcn_mfma_f32_16x16x32_bf16(afr[m], bfr[n], acc[m][n], 0, 0, 0);
        }
    }

#pragma unroll
    for (int n = 0; n < 4; ++n) {
        int col = bn * 128 + wc * 64 + n * 16 + row16;
        float bv = bias[col];
#pragma unroll
        for (int m = 0; m < 4; ++m) {
            int rbase = bm * 128 + wr * 64 + m * 16 + kq * 4;
#pragma unroll
            for (int j = 0; j < 4; ++j)
                out[(size_t)(rbase + j) * OUTF + col] = acc[m][n][j] + bv;
        }
    }
}

extern "C" void kernel_launch(void* const* d_in, const int* in_sizes, int n_in,
                              void* d_out, int out_size, void* d_ws, size_t ws_size,
                              hipStream_t stream) {
    const float* x    = (const float*)d_in[0];
    const int*   wq   = (const int*)d_in[1];
    const float* wn   = (const float*)d_in[2];
    const float* bias = (const float*)d_in[3];
    float* out = (float*)d_out;

    const size_t xb_bytes = (size_t)MROWS * INF * 2;  // 32 MB
    const size_t wb_bytes = (size_t)OUTF * INF * 2;   // 32 MB
    if (ws_size >= xb_bytes + wb_bytes) {
        __bf16* xb = (__bf16*)d_ws;
        __bf16* wb = (__bf16*)((char*)d_ws + xb_bytes);
        prep_kernel<<<8192 + (OUTF * INF / GS) / 256, 256, 0, stream>>>(x, xb, wq, wn, wb);
        gemm3_kernel<<<(MROWS / 256) * (OUTF / 128), 512, 0, stream>>>(xb, wb, bias, out);
    } else {
        gemm_fb_kernel<<<dim3(OUTF / 128, MROWS / 128), 256, 0, stream>>>(x, wq, wn, bias, out);
    }
}